// Round 19
// baseline (85.509 us; speedup 1.0000x reference)
//
#include <hip/hip_runtime.h>
#include <hip/hip_bf16.h>

#define BB 2
#define NN 4096
#define DD 1024
#define HH 16
#define RR 4
#define MM 8
#define CC 64
#define DH 64
#define PAD 68

typedef __attribute__((ext_vector_type(8))) short bf16x8;
typedef __attribute__((ext_vector_type(8))) unsigned short ushort8;
typedef __attribute__((ext_vector_type(4))) float f32x4;
typedef unsigned long long u64;

__device__ __forceinline__ unsigned short f2bf(float x) {  // RNE via HW cvt
  union { __hip_bfloat16 b; unsigned short u; } cv;
  cv.b = __float2bfloat16(x);
  return cv.u;
}
__device__ __forceinline__ float bf2f(unsigned short s) {
  return __uint_as_float(((unsigned)s) << 16);
}
// swizzled byte address in a [64 rows][128 B] LDS tile (16B-granule XOR)
__device__ __forceinline__ int swz(int row, int colbyte) {
  return row * 128 + (colbyte ^ ((row & 7) << 4));
}
__device__ __forceinline__ bf16x8 pack8(float4 a, float4 b, float sc) {
  bf16x8 r;
  const float* pa = (const float*)&a;
  const float* pb = (const float*)&b;
#pragma unroll
  for (int j = 0; j < 4; ++j) {
    r[j] = (short)f2bf(pa[j] * sc);
    r[j + 4] = (short)f2bf(pb[j] * sc);
  }
  return r;
}

// ---------------------------------------------------------------------------
// Kernel P: fused prep (r15-proven, unchanged).
//  blocks [0,1024):    K/V f32 -> bf16 head-major panels [b][h][n][64]
//  blocks [1024,3072): LSH hash codes — wave w owns round r=w, lane owns row.
//    Q staged to LDS cooperatively (coalesced), row read into 64 VGPRs ONCE;
//    P via wave-uniform scalar loads; serial ascending-k chain (bit-identical).
// ---------------------------------------------------------------------------
__global__ __launch_bounds__(256) void k_prep(const float* __restrict__ kmat,
                                              const float* __restrict__ vmat,
                                              const float* __restrict__ q,
                                              const float* __restrict__ proj,
                                              unsigned short* __restrict__ kbf,
                                              unsigned short* __restrict__ vbf,
                                              int* __restrict__ codes) {
  __shared__ float Qs[64][PAD];
  int bid = blockIdx.x;
  int tid = threadIdx.x;

  if (bid < 1024) {  // ---- cvt role ----
    int sel = bid >> 9;
    int rest = bid & 511;
    int b = rest >> 8;
    int chunk = rest & 255;
    const float* src = sel ? vmat : kmat;
    unsigned short* dst = sel ? vbf : kbf;
    int row = chunk * 16 + (tid >> 4), q4 = tid & 15;
    const float* s0 = src + (size_t)(b * NN + row) * DD + q4 * 4;
    unsigned short* d0 = dst + (size_t)b * HH * NN * 64 + (size_t)row * 64 + q4 * 4;
#pragma unroll 4
    for (int h = 0; h < HH; ++h) {
      float4 a = *(const float4*)(s0 + h * 64);
      const float* af = (const float*)&a;
      u64 o = (u64)f2bf(af[0]) | ((u64)f2bf(af[1]) << 16) |
              ((u64)f2bf(af[2]) << 32) | ((u64)f2bf(af[3]) << 48);
      *(u64*)(d0 + (size_t)h * NN * 64) = o;
    }
    return;
  }

  // ---- hash role ----
  int blk = bid - 1024;
  int nc = blk & (CC - 1);
  int h = (blk >> 6) & (HH - 1);
  int b = blk >> 10;
  const float* qbase = q + ((size_t)(b * NN + nc * 64) * DD + h * DH);
  for (int f = tid; f < 1024; f += 256) {
    int row = f >> 4, c4 = f & 15;
    *(float4*)&Qs[row][c4 * 4] = *(const float4*)(qbase + (size_t)row * DD + c4 * 4);
  }
  __syncthreads();

  int lane = tid & 63;
  int ru = __builtin_amdgcn_readfirstlane(tid >> 6);  // wave-uniform r -> s_load P

  float qreg[64];
#pragma unroll
  for (int kq = 0; kq < 16; ++kq) {
    float4 t = *(const float4*)&Qs[lane][kq * 4];
    qreg[4 * kq + 0] = t.x; qreg[4 * kq + 1] = t.y;
    qreg[4 * kq + 2] = t.z; qreg[4 * kq + 3] = t.w;
  }

  const float* pr = proj + (size_t)(ru * HH + h) * DH * MM;
  float acc[8];
#pragma unroll
  for (int m = 0; m < 8; ++m) acc[m] = 0.f;
#pragma unroll
  for (int kk = 0; kk < 64; ++kk) {  // serial ascending-k chain (bit-identical)
    float4 p0 = *(const float4*)(pr + kk * 8);
    float4 p1 = *(const float4*)(pr + kk * 8 + 4);
    float qv = qreg[kk];
    acc[0] += qv * p0.x; acc[1] += qv * p0.y;
    acc[2] += qv * p0.z; acc[3] += qv * p0.w;
    acc[4] += qv * p1.x; acc[5] += qv * p1.y;
    acc[6] += qv * p1.z; acc[7] += qv * p1.w;
  }
  float best = acc[0];
  int bm = 0;
#pragma unroll
  for (int mm = 1; mm < MM; ++mm)
    if (acc[mm] > best) { best = acc[mm]; bm = mm; }  // first-max (jnp.argmax)
  codes[(size_t)((b * RR + ru) * HH + h) * NN + nc * 64 + lane] = bm;
}

// ---------------------------------------------------------------------------
// Kernel 2: stable counting sort via packed-u64 wave scan (unchanged).
// Valence scaling is a positive-integer monotone map -> argsort invariant.
// ---------------------------------------------------------------------------
__global__ __launch_bounds__(256) void k_sort(const int* __restrict__ codes,
                                              int* __restrict__ idxo) {
  int gblk = blockIdx.x;
  const int* cg = codes + (size_t)gblk * NN;
  int* ig = idxo + (size_t)gblk * NN;
  int tid = threadIdx.x, lane = tid & 63, w = tid >> 6;
  __shared__ u64 wtot[4][2];
  int myc[16];
#pragma unroll
  for (int qd = 0; qd < 4; ++qd) {
    int4 t4 = ((const int4*)(cg + tid * 16))[qd];
    myc[qd * 4 + 0] = t4.x; myc[qd * 4 + 1] = t4.y;
    myc[qd * 4 + 2] = t4.z; myc[qd * 4 + 3] = t4.w;
  }
  u64 c01 = 0, c23 = 0;
#pragma unroll
  for (int i = 0; i < 16; ++i) {
    int k = myc[i];
    u64 one = 1ull << (16 * (k & 3));
    if (k < 4) c01 += one; else c23 += one;
  }
  u64 i01 = c01, i23 = c23;
#pragma unroll
  for (int d = 1; d < 64; d <<= 1) {
    u64 t0 = __shfl_up(i01, d);
    u64 t1 = __shfl_up(i23, d);
    if (lane >= d) { i01 += t0; i23 += t1; }
  }
  if (lane == 63) { wtot[w][0] = i01; wtot[w][1] = i23; }
  __syncthreads();
  u64 base01 = 0, base23 = 0, g01 = 0, g23 = 0;
#pragma unroll
  for (int ww = 0; ww < 4; ++ww) {
    u64 a = wtot[ww][0], bq = wtot[ww][1];
    if (ww < w) { base01 += a; base23 += bq; }
    g01 += a; g23 += bq;
  }
  u64 p01 = g01 + (g01 << 16); p01 += (p01 << 32);
  u64 p23 = g23 + (g23 << 16); p23 += (p23 << 32);
  u64 cb01 = p01 << 16;
  u64 tot01 = (p01 >> 48) & 0xffffull;
  u64 cb23 = (p23 << 16) + tot01 * 0x0001000100010001ull;
  u64 o01 = cb01 + base01 + (i01 - c01);
  u64 o23 = cb23 + base23 + (i23 - c23);
#pragma unroll
  for (int i = 0; i < 16; ++i) {
    int k = myc[i];
    int sh = 16 * (k & 3);
    int off;
    if (k < 4) { off = (int)((o01 >> sh) & 0xffffull); o01 += 1ull << sh; }
    else       { off = (int)((o23 >> sh) & 0xffffull); o23 += 1ull << sh; }
    ig[off] = tid * 16 + i;
  }
}

// ---------------------------------------------------------------------------
// per-bucket writeback (O^T layout: lane (g,cl) holds d=16t+4g+i for s=16w+cl)
// ---------------------------------------------------------------------------
__device__ __forceinline__ void write_c(const f32x4* acc_o, const float attA[4][4],
                                        int b, int h, int cblk, int w, int g, int cl,
                                        float* __restrict__ out,
                                        unsigned short* __restrict__ attn_part,
                                        float* __restrict__ attn_out, int atomic_attn) {
  int srow = 16 * w + cl;
  size_t ob = (size_t)(b * NN + cblk * 64 + srow) * DD + h * DH + 4 * g;
#pragma unroll
  for (int t = 0; t < 4; ++t) {
    float4 o = make_float4(acc_o[t][0] * 0.25f, acc_o[t][1] * 0.25f,
                           acc_o[t][2] * 0.25f, acc_o[t][3] * 0.25f);
    *(float4*)(out + ob + 16 * t) = o;
  }
  if (atomic_attn) {
    const float sc = 1.f / (RR * HH);
    size_t abase = (((size_t)b * CC + cblk) * 64 + srow) * 64 + 4 * g;
#pragma unroll
    for (int t = 0; t < 4; ++t)
#pragma unroll
      for (int i = 0; i < 4; ++i)
        atomicAdd(attn_out + abase + 16 * t + i, attA[t][i] * sc);
  } else {
    unsigned short* ap =
        attn_part + (((size_t)(b * HH + h) * CC + cblk) * 64 + srow) * 64 + 4 * g;
#pragma unroll
    for (int t = 0; t < 4; ++t) {
      u64 pk = (u64)f2bf(attA[t][0]) | ((u64)f2bf(attA[t][1]) << 16) |
               ((u64)f2bf(attA[t][2]) << 32) | ((u64)f2bf(attA[t][3]) << 48);
      *(u64*)(ap + 16 * t) = pk;
    }
  }
}

// ---------------------------------------------------------------------------
// Kernel 3: bucketed attention, CG=2 bucket pairing. Block = (b,h,2 buckets),
// grid 1024, 8 fully-unrolled (cq,r) iterations. Inner body, LDS layout
// (25KB: KB+VT+PL single-buffered), barrier structure, swizzles all byte-
// identical to r18's proven loop — only per-block fixed costs (sidx, Q-frags,
// exposed first stage, launch/drain) are amortized 2x.
// ---------------------------------------------------------------------------
__global__ __launch_bounds__(256, 4) void k_attn(const float* __restrict__ q,
                                                 const unsigned short* __restrict__ kbf,
                                                 const unsigned short* __restrict__ vbf,
                                                 const int* __restrict__ idxs,
                                                 float* __restrict__ out,
                                                 unsigned short* __restrict__ attn_part,
                                                 float* __restrict__ attn_out,
                                                 int atomic_attn) {
  __shared__ __align__(16) char KB[8192];   // K bf16 tile, single buffer
  __shared__ __align__(16) char VT[8192];   // V^T bf16, swizzled
  __shared__ __align__(16) char PL[8192];   // P bf16 [s][e], wave-private 2K rows
  __shared__ int sidx[2][RR][64];

  // XCD-aware bijective swizzle: 1024 blocks, 8 XCDs, chunk 128
  int bid = blockIdx.x;
  int blk = (bid & 7) * 128 + (bid >> 3);
  int cgi = blk & 31;
  int h = (blk >> 5) & 15;
  int b = blk >> 9;
  int cbase = cgi * 2;
  int tid = threadIdx.x;
  int lane = tid & 63;
  int w = tid >> 6;
  int g = lane >> 4;
  int cl = lane & 15;
  int e2 = tid & 31, dg = (tid >> 5) & 7;  // V staging roles

  // sidx for both buckets x all rounds: 512 ints, 2 coalesced loads/thread
#pragma unroll
  for (int f0 = 0; f0 < 2; ++f0) {
    int f = tid + f0 * 256;
    int cq = f >> 8, r = (f >> 6) & 3, e = f & 63;
    sidx[cq][r][e] =
        idxs[(size_t)((b * RR + r) * HH + h) * NN + (cbase + cq) * 64 + e];
  }

  const unsigned short* kp = kbf + (size_t)(b * HH + h) * NN * 64;
  const unsigned short* vp = vbf + (size_t)(b * HH + h) * NN * 64;

  // ---- Q fragments for BOTH buckets (pre-scaled by 1/8) ----
  bf16x8 qh[2][2];
#pragma unroll
  for (int cq = 0; cq < 2; ++cq) {
    const float* qrow =
        q + (size_t)(b * NN + (cbase + cq) * 64 + 16 * w + cl) * DD + h * DH;
#pragma unroll
    for (int ks = 0; ks < 2; ++ks)
      qh[cq][ks] = pack8(*(const float4*)(qrow + 32 * ks + 8 * g),
                         *(const float4*)(qrow + 32 * ks + 8 * g + 4), 0.125f);
  }

  __syncthreads();  // sidx visible

  // ---- prologue: K(0,0)+V(0,0) reg loads, stage to LDS ----
  {
    const unsigned short* kr = kp + (size_t)sidx[0][0][16 * w + cl] * 64 + g * 8;
    ushort8 k0a = *(const ushort8*)kr;
    ushort8 k0b = *(const ushort8*)(kr + 32);
    ushort8 v0r = *(const ushort8*)(vp + (size_t)sidx[0][0][2 * e2] * 64 + dg * 8);
    ushort8 v1r = *(const ushort8*)(vp + (size_t)sidx[0][0][2 * e2 + 1] * 64 + dg * 8);
    *(ushort8*)(KB + w * 2048 + g * 256 + cl * 16) = k0a;
    *(ushort8*)(KB + w * 2048 + 1024 + g * 256 + cl * 16) = k0b;
#pragma unroll
    for (int j = 0; j < 8; ++j) {
      unsigned pk = (unsigned)(unsigned short)v0r[j] |
                    ((unsigned)(unsigned short)v1r[j] << 16);
      *(unsigned*)(VT + swz(8 * dg + j, 4 * e2)) = pk;
    }
  }
  __syncthreads();  // KB/VT(0,0) visible

  f32x4 acc_o[4];
  float attA[4][4];
#pragma unroll
  for (int t = 0; t < 4; ++t) {
    acc_o[t] = (f32x4){0.f, 0.f, 0.f, 0.f};
#pragma unroll
    for (int i = 0; i < 4; ++i) attA[t][i] = 0.f;
  }

#pragma unroll
  for (int it = 0; it < 2 * RR; ++it) {
    const int cq = it >> 2;

    // ---- prefetch (it+1) into registers (at TOP; waited only at ds_write) ----
    ushort8 kna, knb, n0r, n1r;
    if (it < 2 * RR - 1) {
      const int* sn = sidx[(it + 1) >> 2][(it + 1) & 3];
      const unsigned short* krn = kp + (size_t)sn[16 * w + cl] * 64 + g * 8;
      kna = *(const ushort8*)krn;
      knb = *(const ushort8*)(krn + 32);
      n0r = *(const ushort8*)(vp + (size_t)sn[2 * e2] * 64 + dg * 8);
      n1r = *(const ushort8*)(vp + (size_t)sn[2 * e2 + 1] * 64 + dg * 8);
    }

    // ---- QK^T swapped: S^T[e][s]; C: e_local=4g+i (tile t), s=cl ----
    f32x4 s4[4];
#pragma unroll
    for (int t = 0; t < 4; ++t) s4[t] = (f32x4){0.f, 0.f, 0.f, 0.f};
    __builtin_amdgcn_s_setprio(1);
#pragma unroll
    for (int t = 0; t < 4; ++t)
#pragma unroll
      for (int ks = 0; ks < 2; ++ks) {
        bf16x8 kf = *(const bf16x8*)(KB + t * 2048 + ks * 1024 + g * 256 + cl * 16);
        s4[t] = __builtin_amdgcn_mfma_f32_16x16x32_bf16(kf, qh[cq][ks], s4[t], 0, 0, 0);
      }
    __builtin_amdgcn_s_setprio(0);

    // ---- softmax over e: in-lane tree (16 regs) + 2 shfl_xor over g-lanes ----
    {
      f32x4 m4 = s4[0];
#pragma unroll
      for (int t = 1; t < 4; ++t)
#pragma unroll
        for (int i = 0; i < 4; ++i) m4[i] = fmaxf(m4[i], s4[t][i]);
      float mx = fmaxf(fmaxf(m4[0], m4[1]), fmaxf(m4[2], m4[3]));
      mx = fmaxf(mx, __shfl_xor(mx, 16));
      mx = fmaxf(mx, __shfl_xor(mx, 32));
      float sm = 0.f;
#pragma unroll
      for (int t = 0; t < 4; ++t)
#pragma unroll
        for (int i = 0; i < 4; ++i) {
          float e = __expf(s4[t][i] - mx);
          s4[t][i] = e;
          sm += e;
        }
      sm += __shfl_xor(sm, 16);
      sm += __shfl_xor(sm, 32);
      float inv = __builtin_amdgcn_rcpf(sm);
#pragma unroll
      for (int t = 0; t < 4; ++t)
#pragma unroll
        for (int i = 0; i < 4; ++i) {
          s4[t][i] *= inv;
          attA[t][i] += s4[t][i];
        }
    }

    // ---- P -> PL[s=cl][e] (4x ds_write_b64, wave-private; no barrier) ----
#pragma unroll
    for (int t = 0; t < 4; ++t) {
      u64 pk = (u64)f2bf(s4[t][0]) | ((u64)f2bf(s4[t][1]) << 16) |
               ((u64)f2bf(s4[t][2]) << 32) | ((u64)f2bf(s4[t][3]) << 48);
      *(u64*)(PL + w * 2048 + swz(cl, 32 * t + 8 * g)) = pk;
    }
    bf16x8 pa[2];
#pragma unroll
    for (int ks = 0; ks < 2; ++ks)
      pa[ks] = *(const bf16x8*)(PL + w * 2048 + swz(cl, 64 * ks + 16 * g));

    // ---- PV swapped: O^T = mfma(A=V^T, B=P) ----
    __builtin_amdgcn_s_setprio(1);
#pragma unroll
    for (int t = 0; t < 4; ++t)
#pragma unroll
      for (int ks = 0; ks < 2; ++ks) {
        bf16x8 vt = *(const bf16x8*)(VT + swz(16 * t + cl, ks * 64 + g * 16));
        acc_o[t] = __builtin_amdgcn_mfma_f32_16x16x32_bf16(vt, pa[ks], acc_o[t], 0, 0, 0);
      }
    __builtin_amdgcn_s_setprio(0);

    // ---- bucket-0 epilogue (stores drain under the following barrier) ----
    if (it == RR - 1) {
      write_c(acc_o, attA, b, h, cbase, w, g, cl, out, attn_part, attn_out,
              atomic_attn);
#pragma unroll
      for (int t = 0; t < 4; ++t) {
        acc_o[t] = (f32x4){0.f, 0.f, 0.f, 0.f};
#pragma unroll
        for (int i = 0; i < 4; ++i) attA[t][i] = 0.f;
      }
    }

    if (it < 2 * RR - 1) {
      __syncthreads();  // all waves done reading KB/VT(it)
      // ---- stage (it+1): K via 2x ds_write_b128, V via 8x u32 transpose ----
      *(ushort8*)(KB + w * 2048 + g * 256 + cl * 16) = kna;
      *(ushort8*)(KB + w * 2048 + 1024 + g * 256 + cl * 16) = knb;
#pragma unroll
      for (int j = 0; j < 8; ++j) {
        unsigned pk = (unsigned)(unsigned short)n0r[j] |
                      ((unsigned)(unsigned short)n1r[j] << 16);
        *(unsigned*)(VT + swz(8 * dg + j, 4 * e2)) = pk;
      }
      __syncthreads();  // KB/VT(it+1) visible
    }
  }

  write_c(acc_o, attA, b, h, cbase + 1, w, g, cl, out, attn_part, attn_out,
          atomic_attn);
}

// ---------------------------------------------------------------------------
// Kernel 4: attn_out = (1/(R*H)) * sum_h attn_part (bf16 partials, unchanged)
// ---------------------------------------------------------------------------
__global__ __launch_bounds__(256) void k_attn_reduce(const unsigned short* __restrict__ part,
                                                     float* __restrict__ attn_out) {
  size_t o = (size_t)blockIdx.x * 256 + threadIdx.x;
  int se = (int)(o & 4095);
  size_t bc = o >> 12;
  int c = (int)(bc & (CC - 1));
  int b = (int)(bc >> 6);
  float s = 0.f;
  const unsigned short* p = part + ((size_t)b * HH * CC + c) * 4096 + se;
#pragma unroll
  for (int h = 0; h < HH; ++h) s += bf2f(p[(size_t)h * CC * 4096]);
  attn_out[o] = s * (1.f / (RR * HH));
}

extern "C" void kernel_launch(void* const* d_in, const int* in_sizes, int n_in,
                              void* d_out, int out_size, void* d_ws, size_t ws_size,
                              hipStream_t stream) {
  const float* q = (const float*)d_in[0];
  const float* k = (const float*)d_in[1];
  const float* v = (const float*)d_in[2];
  // d_in[3] (valence), d_in[5] (valence_scale): positive-int monotone code scale
  // -> argsort order invariant -> dead inputs.
  const float* proj = (const float*)d_in[4];
  float* out = (float*)d_out;
  float* attn_out = out + (size_t)BB * NN * DD;

  const size_t n_codes = (size_t)BB * RR * HH * NN;          // 524288 ints
  const size_t n_panel = (size_t)BB * HH * NN * 64;          // 8388608 bf16 each
  const size_t n_part  = (size_t)BB * HH * CC * 4096;        // 8388608 bf16

  int* codes = (int*)d_ws;
  int* idxs = codes + n_codes;
  unsigned short* kbf = (unsigned short*)(idxs + n_codes);
  unsigned short* vbf = kbf + n_panel;
  unsigned short* attn_part = vbf + n_panel;

  size_t need_full = n_codes * 8 + n_panel * 4 + n_part * 2;
  int atomic_attn = (ws_size < need_full) ? 1 : 0;
  if (atomic_attn)
    hipMemsetAsync(attn_out, 0, (size_t)BB * CC * 4096 * sizeof(float), stream);

  k_prep<<<1024 + BB * HH * CC, 256, 0, stream>>>(k, v, q, proj, kbf, vbf, codes);
  k_sort<<<BB * RR * HH, 256, 0, stream>>>(codes, idxs);
  k_attn<<<BB * HH * (CC / 2), 256, 0, stream>>>(q, kbf, vbf, idxs, out, attn_part,
                                                 attn_out, atomic_attn);
  if (!atomic_attn)
    k_attn_reduce<<<BB * CC * 4096 / 256, 256, 0, stream>>>(attn_part, attn_out);
}

// Round 20
// 77.896 us; speedup vs baseline: 1.0977x; 1.0977x over previous
//
#include <hip/hip_runtime.h>
#include <hip/hip_bf16.h>

#define BB 2
#define NN 4096
#define DD 1024
#define HH 16
#define RR 4
#define MM 8
#define CC 64
#define DH 64
#define PAD 68

typedef __attribute__((ext_vector_type(8))) short bf16x8;
typedef __attribute__((ext_vector_type(8))) unsigned short ushort8;
typedef __attribute__((ext_vector_type(4))) float f32x4;
typedef unsigned long long u64;

__device__ __forceinline__ unsigned short f2bf(float x) {  // RNE via HW cvt
  union { __hip_bfloat16 b; unsigned short u; } cv;
  cv.b = __float2bfloat16(x);
  return cv.u;
}
__device__ __forceinline__ float bf2f(unsigned short s) {
  return __uint_as_float(((unsigned)s) << 16);
}
// swizzled byte address in a [64 rows][128 B] LDS tile (16B-granule XOR)
__device__ __forceinline__ int swz(int row, int colbyte) {
  return row * 128 + (colbyte ^ ((row & 7) << 4));
}
__device__ __forceinline__ bf16x8 pack8(float4 a, float4 b, float sc) {
  bf16x8 r;
  const float* pa = (const float*)&a;
  const float* pb = (const float*)&b;
#pragma unroll
  for (int j = 0; j < 4; ++j) {
    r[j] = (short)f2bf(pa[j] * sc);
    r[j + 4] = (short)f2bf(pb[j] * sc);
  }
  return r;
}

// ---------------------------------------------------------------------------
// Kernel P: fused prep (r15/r18-proven version).
//  blocks [0,1024):    K/V f32 -> bf16 head-major panels [b][h][n][64]
//  blocks [1024,3072): LSH hash codes — wave w owns round r=w, lane owns row.
//    Q staged to LDS cooperatively (coalesced), row read into 64 VGPRs ONCE;
//    P via wave-uniform scalar loads (readfirstlane -> s_load, zero LDS);
//    per-(row,m) FMA chain is serial ascending-k -> bit-identical codes.
// ---------------------------------------------------------------------------
__global__ __launch_bounds__(256) void k_prep(const float* __restrict__ kmat,
                                              const float* __restrict__ vmat,
                                              const float* __restrict__ q,
                                              const float* __restrict__ proj,
                                              unsigned short* __restrict__ kbf,
                                              unsigned short* __restrict__ vbf,
                                              int* __restrict__ codes) {
  __shared__ float Qs[64][PAD];
  int bid = blockIdx.x;
  int tid = threadIdx.x;

  if (bid < 1024) {  // ---- cvt role ----
    int sel = bid >> 9;
    int rest = bid & 511;
    int b = rest >> 8;
    int chunk = rest & 255;
    const float* src = sel ? vmat : kmat;
    unsigned short* dst = sel ? vbf : kbf;
    int row = chunk * 16 + (tid >> 4), q4 = tid & 15;
    const float* s0 = src + (size_t)(b * NN + row) * DD + q4 * 4;
    unsigned short* d0 = dst + (size_t)b * HH * NN * 64 + (size_t)row * 64 + q4 * 4;
#pragma unroll 4
    for (int h = 0; h < HH; ++h) {
      float4 a = *(const float4*)(s0 + h * 64);
      const float* af = (const float*)&a;
      u64 o = (u64)f2bf(af[0]) | ((u64)f2bf(af[1]) << 16) |
              ((u64)f2bf(af[2]) << 32) | ((u64)f2bf(af[3]) << 48);
      *(u64*)(d0 + (size_t)h * NN * 64) = o;
    }
    return;
  }

  // ---- hash role ----
  int blk = bid - 1024;
  int nc = blk & (CC - 1);
  int h = (blk >> 6) & (HH - 1);
  int b = blk >> 10;
  const float* qbase = q + ((size_t)(b * NN + nc * 64) * DD + h * DH);
  for (int f = tid; f < 1024; f += 256) {
    int row = f >> 4, c4 = f & 15;
    *(float4*)&Qs[row][c4 * 4] = *(const float4*)(qbase + (size_t)row * DD + c4 * 4);
  }
  __syncthreads();

  int lane = tid & 63;
  int ru = __builtin_amdgcn_readfirstlane(tid >> 6);  // wave-uniform r -> s_load P

  float qreg[64];
#pragma unroll
  for (int kq = 0; kq < 16; ++kq) {
    float4 t = *(const float4*)&Qs[lane][kq * 4];
    qreg[4 * kq + 0] = t.x; qreg[4 * kq + 1] = t.y;
    qreg[4 * kq + 2] = t.z; qreg[4 * kq + 3] = t.w;
  }

  const float* pr = proj + (size_t)(ru * HH + h) * DH * MM;
  float acc[8];
#pragma unroll
  for (int m = 0; m < 8; ++m) acc[m] = 0.f;
#pragma unroll
  for (int kk = 0; kk < 64; ++kk) {  // serial ascending-k chain (bit-identical)
    float4 p0 = *(const float4*)(pr + kk * 8);      // uniform -> s_load_dwordx4
    float4 p1 = *(const float4*)(pr + kk * 8 + 4);
    float qv = qreg[kk];
    acc[0] += qv * p0.x; acc[1] += qv * p0.y;
    acc[2] += qv * p0.z; acc[3] += qv * p0.w;
    acc[4] += qv * p1.x; acc[5] += qv * p1.y;
    acc[6] += qv * p1.z; acc[7] += qv * p1.w;
  }
  float best = acc[0];
  int bm = 0;
#pragma unroll
  for (int mm = 1; mm < MM; ++mm)
    if (acc[mm] > best) { best = acc[mm]; bm = mm; }  // first-max (jnp.argmax)
  codes[(size_t)((b * RR + ru) * HH + h) * NN + nc * 64 + lane] = bm;
}

// ---------------------------------------------------------------------------
// Kernel 2: stable counting sort via packed-u64 wave scan.
// Valence scaling is a positive-integer monotone map -> argsort invariant.
// ---------------------------------------------------------------------------
__global__ __launch_bounds__(256) void k_sort(const int* __restrict__ codes,
                                              int* __restrict__ idxo) {
  int gblk = blockIdx.x;
  const int* cg = codes + (size_t)gblk * NN;
  int* ig = idxo + (size_t)gblk * NN;
  int tid = threadIdx.x, lane = tid & 63, w = tid >> 6;
  __shared__ u64 wtot[4][2];
  int myc[16];
#pragma unroll
  for (int qd = 0; qd < 4; ++qd) {
    int4 t4 = ((const int4*)(cg + tid * 16))[qd];
    myc[qd * 4 + 0] = t4.x; myc[qd * 4 + 1] = t4.y;
    myc[qd * 4 + 2] = t4.z; myc[qd * 4 + 3] = t4.w;
  }
  u64 c01 = 0, c23 = 0;
#pragma unroll
  for (int i = 0; i < 16; ++i) {
    int k = myc[i];
    u64 one = 1ull << (16 * (k & 3));
    if (k < 4) c01 += one; else c23 += one;
  }
  u64 i01 = c01, i23 = c23;
#pragma unroll
  for (int d = 1; d < 64; d <<= 1) {
    u64 t0 = __shfl_up(i01, d);
    u64 t1 = __shfl_up(i23, d);
    if (lane >= d) { i01 += t0; i23 += t1; }
  }
  if (lane == 63) { wtot[w][0] = i01; wtot[w][1] = i23; }
  __syncthreads();
  u64 base01 = 0, base23 = 0, g01 = 0, g23 = 0;
#pragma unroll
  for (int ww = 0; ww < 4; ++ww) {
    u64 a = wtot[ww][0], bq = wtot[ww][1];
    if (ww < w) { base01 += a; base23 += bq; }
    g01 += a; g23 += bq;
  }
  u64 p01 = g01 + (g01 << 16); p01 += (p01 << 32);
  u64 p23 = g23 + (g23 << 16); p23 += (p23 << 32);
  u64 cb01 = p01 << 16;
  u64 tot01 = (p01 >> 48) & 0xffffull;
  u64 cb23 = (p23 << 16) + tot01 * 0x0001000100010001ull;
  u64 o01 = cb01 + base01 + (i01 - c01);
  u64 o23 = cb23 + base23 + (i23 - c23);
#pragma unroll
  for (int i = 0; i < 16; ++i) {
    int k = myc[i];
    int sh = 16 * (k & 3);
    int off;
    if (k < 4) { off = (int)((o01 >> sh) & 0xffffull); o01 += 1ull << sh; }
    else       { off = (int)((o23 >> sh) & 0xffffull); o23 += 1ull << sh; }
    ig[off] = tid * 16 + i;
  }
}

// ---------------------------------------------------------------------------
// Kernel 3: bucketed attention — r13/r14/r15/r18-proven, byte-identical.
// Block=(b,h,c): 64 blocks per (b,h) panel keeps K/V panel L2-resident
// (4 panels x 1MB = exactly the 4MB XCD L2) for the 4x r-round gather reuse.
// ---------------------------------------------------------------------------
__global__ __launch_bounds__(256, 4) void k_attn(const float* __restrict__ q,
                                                 const unsigned short* __restrict__ kbf,
                                                 const unsigned short* __restrict__ vbf,
                                                 const int* __restrict__ idxs,
                                                 float* __restrict__ out,
                                                 unsigned short* __restrict__ attn_part,
                                                 float* __restrict__ attn_out,
                                                 int atomic_attn) {
  __shared__ __align__(16) char KB[8192];   // K bf16 tile, single buffer
  __shared__ __align__(16) char VT[8192];   // V^T bf16, swizzled
  __shared__ __align__(16) char PL[8192];   // P bf16 [s][e], wave-private 2K rows
  __shared__ int sidx[RR][64];

  // XCD-aware bijective swizzle: 2048 blocks, 8 XCDs, chunk 256
  int bid = blockIdx.x;
  int blk = (bid & 7) * 256 + (bid >> 3);
  int cblk = blk & 63;
  int h = (blk >> 6) & 15;
  int b = blk >> 10;
  int tid = threadIdx.x;
  int lane = tid & 63;
  int w = tid >> 6;
  int g = lane >> 4;
  int cl = lane & 15;
  int e2 = tid & 31, dg = (tid >> 5) & 7;  // V staging roles

  sidx[tid >> 6][tid & 63] =
      idxs[(size_t)((b * RR + (tid >> 6)) * HH + h) * NN + cblk * 64 + (tid & 63)];

  const unsigned short* kp = kbf + (size_t)(b * HH + h) * NN * 64;
  const unsigned short* vp = vbf + (size_t)(b * HH + h) * NN * 64;

  // ---- Q fragments (B-operand of QK^T), pre-scaled by 1/8 ----
  const float* qrow = q + (size_t)(b * NN + cblk * 64 + 16 * w + cl) * DD + h * DH;
  bf16x8 qh[2];
#pragma unroll
  for (int ks = 0; ks < 2; ++ks)
    qh[ks] = pack8(*(const float4*)(qrow + 32 * ks + 8 * g),
                   *(const float4*)(qrow + 32 * ks + 8 * g + 4), 0.125f);

  __syncthreads();  // sidx visible

  // ---- prologue: K(0)+V(0) reg loads, stage to LDS ----
  {
    const unsigned short* kr = kp + (size_t)sidx[0][16 * w + cl] * 64 + g * 8;
    ushort8 k0a = *(const ushort8*)kr;
    ushort8 k0b = *(const ushort8*)(kr + 32);
    ushort8 v0r = *(const ushort8*)(vp + (size_t)sidx[0][2 * e2] * 64 + dg * 8);
    ushort8 v1r = *(const ushort8*)(vp + (size_t)sidx[0][2 * e2 + 1] * 64 + dg * 8);
    *(ushort8*)(KB + w * 2048 + g * 256 + cl * 16) = k0a;
    *(ushort8*)(KB + w * 2048 + 1024 + g * 256 + cl * 16) = k0b;
#pragma unroll
    for (int j = 0; j < 8; ++j) {
      unsigned pk = (unsigned)(unsigned short)v0r[j] |
                    ((unsigned)(unsigned short)v1r[j] << 16);
      *(unsigned*)(VT + swz(8 * dg + j, 4 * e2)) = pk;
    }
  }
  __syncthreads();  // KB/VT(0) visible

  f32x4 acc_o[4];
  float attA[4][4];
#pragma unroll
  for (int t = 0; t < 4; ++t) {
    acc_o[t] = (f32x4){0.f, 0.f, 0.f, 0.f};
#pragma unroll
    for (int i = 0; i < 4; ++i) attA[t][i] = 0.f;
  }

#pragma unroll
  for (int r = 0; r < RR; ++r) {
    // ---- prefetch (r+1) into registers (at TOP; waited only at ds_write) ----
    ushort8 kna, knb, n0r, n1r;
    if (r < RR - 1) {
      const unsigned short* krn = kp + (size_t)sidx[r + 1][16 * w + cl] * 64 + g * 8;
      kna = *(const ushort8*)krn;
      knb = *(const ushort8*)(krn + 32);
      n0r = *(const ushort8*)(vp + (size_t)sidx[r + 1][2 * e2] * 64 + dg * 8);
      n1r = *(const ushort8*)(vp + (size_t)sidx[r + 1][2 * e2 + 1] * 64 + dg * 8);
    }

    // ---- QK^T swapped: S^T[e][s]; C: e_local=4g+i (tile t), s=cl ----
    f32x4 s4[4];
#pragma unroll
    for (int t = 0; t < 4; ++t) s4[t] = (f32x4){0.f, 0.f, 0.f, 0.f};
    __builtin_amdgcn_s_setprio(1);
#pragma unroll
    for (int t = 0; t < 4; ++t)
#pragma unroll
      for (int ks = 0; ks < 2; ++ks) {
        bf16x8 kf = *(const bf16x8*)(KB + t * 2048 + ks * 1024 + g * 256 + cl * 16);
        s4[t] = __builtin_amdgcn_mfma_f32_16x16x32_bf16(kf, qh[ks], s4[t], 0, 0, 0);
      }
    __builtin_amdgcn_s_setprio(0);

    // ---- softmax over e: in-lane tree (16 regs) + 2 shfl_xor over g-lanes ----
    {
      f32x4 m4 = s4[0];
#pragma unroll
      for (int t = 1; t < 4; ++t)
#pragma unroll
        for (int i = 0; i < 4; ++i) m4[i] = fmaxf(m4[i], s4[t][i]);
      float mx = fmaxf(fmaxf(m4[0], m4[1]), fmaxf(m4[2], m4[3]));
      mx = fmaxf(mx, __shfl_xor(mx, 16));
      mx = fmaxf(mx, __shfl_xor(mx, 32));
      float sm = 0.f;
#pragma unroll
      for (int t = 0; t < 4; ++t)
#pragma unroll
        for (int i = 0; i < 4; ++i) {
          float e = __expf(s4[t][i] - mx);
          s4[t][i] = e;
          sm += e;
        }
      sm += __shfl_xor(sm, 16);
      sm += __shfl_xor(sm, 32);
      float inv = __builtin_amdgcn_rcpf(sm);
#pragma unroll
      for (int t = 0; t < 4; ++t)
#pragma unroll
        for (int i = 0; i < 4; ++i) {
          s4[t][i] *= inv;
          attA[t][i] += s4[t][i];
        }
    }

    // ---- P -> PL[s=cl][e] (4x ds_write_b64, wave-private; no barrier) ----
#pragma unroll
    for (int t = 0; t < 4; ++t) {
      u64 pk = (u64)f2bf(s4[t][0]) | ((u64)f2bf(s4[t][1]) << 16) |
               ((u64)f2bf(s4[t][2]) << 32) | ((u64)f2bf(s4[t][3]) << 48);
      *(u64*)(PL + w * 2048 + swz(cl, 32 * t + 8 * g)) = pk;
    }
    bf16x8 pa[2];
#pragma unroll
    for (int ks = 0; ks < 2; ++ks)
      pa[ks] = *(const bf16x8*)(PL + w * 2048 + swz(cl, 64 * ks + 16 * g));

    // ---- PV swapped: O^T = mfma(A=V^T, B=P) ----
    __builtin_amdgcn_s_setprio(1);
#pragma unroll
    for (int t = 0; t < 4; ++t)
#pragma unroll
      for (int ks = 0; ks < 2; ++ks) {
        bf16x8 vt = *(const bf16x8*)(VT + swz(16 * t + cl, ks * 64 + g * 16));
        acc_o[t] = __builtin_amdgcn_mfma_f32_16x16x32_bf16(vt, pa[ks], acc_o[t], 0, 0, 0);
      }
    __builtin_amdgcn_s_setprio(0);

    if (r < RR - 1) {
      __syncthreads();  // all waves done reading KB/VT(r)
      // ---- stage (r+1): K via 2x ds_write_b128, V via 8x u32 transpose ----
      *(ushort8*)(KB + w * 2048 + g * 256 + cl * 16) = kna;
      *(ushort8*)(KB + w * 2048 + 1024 + g * 256 + cl * 16) = knb;
#pragma unroll
      for (int j = 0; j < 8; ++j) {
        unsigned pk = (unsigned)(unsigned short)n0r[j] |
                      ((unsigned)(unsigned short)n1r[j] << 16);
        *(unsigned*)(VT + swz(8 * dg + j, 4 * e2)) = pk;
      }
      __syncthreads();  // KB/VT(r+1) visible
    }
  }

  // ---- epilogue: lane (g,cl) holds d=16t+4g+i for s=16w+cl ----
  int srow = 16 * w + cl;
  size_t ob = (size_t)(b * NN + cblk * 64 + srow) * DD + h * DH + 4 * g;
#pragma unroll
  for (int t = 0; t < 4; ++t) {
    float4 o = make_float4(acc_o[t][0] * 0.25f, acc_o[t][1] * 0.25f,
                           acc_o[t][2] * 0.25f, acc_o[t][3] * 0.25f);
    *(float4*)(out + ob + 16 * t) = o;
  }
  if (atomic_attn) {
    const float sc = 1.f / (RR * HH);
    size_t abase = (((size_t)b * CC + cblk) * 64 + srow) * 64 + 4 * g;
#pragma unroll
    for (int t = 0; t < 4; ++t)
#pragma unroll
      for (int i = 0; i < 4; ++i)
        atomicAdd(attn_out + abase + 16 * t + i, attA[t][i] * sc);
  } else {
    // bf16 partials: 4x u64 stores (8B aligned)
    unsigned short* ap =
        attn_part + (((size_t)(b * HH + h) * CC + cblk) * 64 + srow) * 64 + 4 * g;
#pragma unroll
    for (int t = 0; t < 4; ++t) {
      u64 pk = (u64)f2bf(attA[t][0]) | ((u64)f2bf(attA[t][1]) << 16) |
               ((u64)f2bf(attA[t][2]) << 32) | ((u64)f2bf(attA[t][3]) << 48);
      *(u64*)(ap + 16 * t) = pk;
    }
  }
}

// ---------------------------------------------------------------------------
// Kernel 4: attn_out = (1/(R*H)) * sum_h attn_part (bf16 partials)
// ---------------------------------------------------------------------------
__global__ __launch_bounds__(256) void k_attn_reduce(const unsigned short* __restrict__ part,
                                                     float* __restrict__ attn_out) {
  size_t o = (size_t)blockIdx.x * 256 + threadIdx.x;
  int se = (int)(o & 4095);
  size_t bc = o >> 12;
  int c = (int)(bc & (CC - 1));
  int b = (int)(bc >> 6);
  float s = 0.f;
  const unsigned short* p = part + ((size_t)b * HH * CC + c) * 4096 + se;
#pragma unroll
  for (int h = 0; h < HH; ++h) s += bf2f(p[(size_t)h * CC * 4096]);
  attn_out[o] = s * (1.f / (RR * HH));
}

extern "C" void kernel_launch(void* const* d_in, const int* in_sizes, int n_in,
                              void* d_out, int out_size, void* d_ws, size_t ws_size,
                              hipStream_t stream) {
  const float* q = (const float*)d_in[0];
  const float* k = (const float*)d_in[1];
  const float* v = (const float*)d_in[2];
  // d_in[3] (valence), d_in[5] (valence_scale): positive-int monotone code scale
  // -> argsort order invariant -> dead inputs.
  const float* proj = (const float*)d_in[4];
  float* out = (float*)d_out;
  float* attn_out = out + (size_t)BB * NN * DD;

  const size_t n_codes = (size_t)BB * RR * HH * NN;          // 524288 ints
  const size_t n_panel = (size_t)BB * HH * NN * 64;          // 8388608 bf16 each
  const size_t n_part  = (size_t)BB * HH * CC * 4096;        // 8388608 bf16

  int* codes = (int*)d_ws;
  int* idxs = codes + n_codes;
  unsigned short* kbf = (unsigned short*)(idxs + n_codes);
  unsigned short* vbf = kbf + n_panel;
  unsigned short* attn_part = vbf + n_panel;

  size_t need_full = n_codes * 8 + n_panel * 4 + n_part * 2;
  int atomic_attn = (ws_size < need_full) ? 1 : 0;
  if (atomic_attn)
    hipMemsetAsync(attn_out, 0, (size_t)BB * CC * 4096 * sizeof(float), stream);

  k_prep<<<1024 + BB * HH * CC, 256, 0, stream>>>(k, v, q, proj, kbf, vbf, codes);
  k_sort<<<BB * RR * HH, 256, 0, stream>>>(codes, idxs);
  k_attn<<<BB * HH * CC, 256, 0, stream>>>(q, kbf, vbf, idxs, out, attn_part,
                                           attn_out, atomic_attn);
  if (!atomic_attn)
    k_attn_reduce<<<BB * CC * 4096 / 256, 256, 0, stream>>>(attn_part, attn_out);
}